// Round 2
// baseline (1043.726 us; speedup 1.0000x reference)
//
#include <hip/hip_runtime.h>
#include <cstdint>
#include <cstddef>

// Problem constants
#define BB 2
#define HB 16
#define LL 2048
#define DD 128
#define MM 4096   // B*L
#define KK 2048   // DIM
#define N1 6144   // 3*DIM
#define N2 2048   // DIM
#define BHLD (BB*HB*LL*DD)  // 8388608 elements per q/k/v section

typedef unsigned short u16;
typedef __bf16 bf16x8 __attribute__((ext_vector_type(8)));   // 4 VGPRs: mfma 16x16x32 A/B operand
typedef short  s16x4  __attribute__((ext_vector_type(4)));   // 2 VGPRs: mfma 16x16x16 (_1k) A/B operand
typedef float  f32x4  __attribute__((ext_vector_type(4)));

__device__ __forceinline__ float bf2f(u16 u) {
  union { unsigned v; float f; } c; c.v = ((unsigned)u) << 16; return c.f;
}
__device__ __forceinline__ u16 f2bf(float f) {  // round-to-nearest-even
  unsigned u = __builtin_bit_cast(unsigned, f);
  return (u16)((u + 0x7FFFu + ((u >> 16) & 1u)) >> 16);
}

// ---------------- prep kernels ----------------

__global__ __launch_bounds__(256) void f32_to_bf16_vec(
    const float* __restrict__ in, u16* __restrict__ out, int n4) {
  int i = blockIdx.x * 256 + threadIdx.x;
  if (i >= n4) return;
  float4 v = ((const float4*)in)[i];
  ushort4 o;
  o.x = f2bf(v.x); o.y = f2bf(v.y); o.z = f2bf(v.z); o.w = f2bf(v.w);
  ((ushort4*)out)[i] = o;
}

// in: fp32 [R][C] row-major  ->  out: bf16 [C][R]
__global__ __launch_bounds__(256) void transpose_f32_bf16(
    const float* __restrict__ in, u16* __restrict__ out, int R, int C) {
  __shared__ float t[32][33];
  int c0 = blockIdx.x * 32, r0 = blockIdx.y * 32;
  int tx = threadIdx.x & 31, ty = threadIdx.x >> 5;  // 8 rows per pass
#pragma unroll
  for (int i = ty; i < 32; i += 8)
    t[i][tx] = in[(size_t)(r0 + i) * C + c0 + tx];
  __syncthreads();
#pragma unroll
  for (int i = ty; i < 32; i += 8)
    out[(size_t)(c0 + i) * R + r0 + tx] = f2bf(t[tx][i]);
}

// ---------------- GEMM (A [M][K] bf16, Bt [N][K] bf16) ----------------
// MODE 0: epilogue scatters into qkv sections: q,k as [B][H][L][D], v as [B][H][D][L] (bf16)
// MODE 1: plain fp32 row-major store [M][N]
template<int MODE>
__global__ __launch_bounds__(256) void gemm_bt(
    const u16* __restrict__ A, const u16* __restrict__ Bt,
    const float* __restrict__ bias, void* __restrict__ Cout,
    int Msz, int Nsz, int Ksz)
{
  __shared__ __align__(16) u16 As[128*32];
  __shared__ __align__(16) u16 Bs[128*32];
  const int tid  = threadIdx.x;
  const int lane = tid & 63;
  const int wid  = tid >> 6;
  const int l15  = lane & 15, quad = lane >> 4;
  const int m0 = blockIdx.y * 128, n0 = blockIdx.x * 128;
  const int wm = (wid >> 1) * 64, wn = (wid & 1) * 64;
  // staging: 512 16B-chunks per tile, 2 per thread; chunk c -> row c>>2, inner (c&3)*8 elems
  const int r0i = tid >> 2, in0 = (tid & 3) * 8;

  f32x4 acc[4][4] = {};

  for (int ks = 0; ks < Ksz; ks += 32) {
    __syncthreads();
    *(uint4*)&As[ r0i      *32 + in0] = *(const uint4*)&A [(size_t)(m0 + r0i)      * Ksz + ks + in0];
    *(uint4*)&As[(r0i + 64)*32 + in0] = *(const uint4*)&A [(size_t)(m0 + r0i + 64) * Ksz + ks + in0];
    *(uint4*)&Bs[ r0i      *32 + in0] = *(const uint4*)&Bt[(size_t)(n0 + r0i)      * Ksz + ks + in0];
    *(uint4*)&Bs[(r0i + 64)*32 + in0] = *(const uint4*)&Bt[(size_t)(n0 + r0i + 64) * Ksz + ks + in0];
    __syncthreads();
    bf16x8 af[4], bfr[4];
#pragma unroll
    for (int i = 0; i < 4; i++) af[i]  = *(const bf16x8*)&As[(wm + i*16 + l15)*32 + quad*8];
#pragma unroll
    for (int i = 0; i < 4; i++) bfr[i] = *(const bf16x8*)&Bs[(wn + i*16 + l15)*32 + quad*8];
#pragma unroll
    for (int i = 0; i < 4; i++)
#pragma unroll
      for (int j = 0; j < 4; j++)
        acc[i][j] = __builtin_amdgcn_mfma_f32_16x16x32_bf16(af[i], bfr[j], acc[i][j], 0, 0, 0);
  }

  // C/D layout: row = quad*4+reg (m), col = lane&15 (n)  [verified m89/m91]
#pragma unroll
  for (int i = 0; i < 4; i++) {
#pragma unroll
    for (int j = 0; j < 4; j++) {
      const int col = n0 + wn + j*16 + l15;
      const float bv = bias[col];
#pragma unroll
      for (int r = 0; r < 4; r++) {
        const int row = m0 + wm + i*16 + quad*4 + r;
        float v = acc[i][j][r] + bv;
        if (MODE == 0) {
          u16* qkv = (u16*)Cout;
          int t = col >> 11, hd = col & 2047, h = hd >> 7, d = hd & 127;
          int b = row >> 11, l = row & (LL - 1);
          size_t dst;
          if (t < 2) dst = (size_t)t * BHLD + (((size_t)(b*HB + h)) * LL + l) * DD + d;
          else       dst = (size_t)2 * BHLD + (((size_t)(b*HB + h)) * DD + d) * LL + l;
          qkv[dst] = f2bf(v);
        } else {
          ((float*)Cout)[(size_t)row * Nsz + col] = v;
        }
      }
    }
  }
}

// ---------------- fused RMSNorm + RoPE on q,k (in place, bf16) ----------------
// one wave per (b,h,l) row of 128; lane owns pair p = lane (D/2 = 64 pairs)
__global__ __launch_bounds__(256) void norm_rope(
    u16* __restrict__ qkv, const float* __restrict__ pe,
    const float* __restrict__ qsc, const float* __restrict__ ksc)
{
  const int wid = threadIdx.x >> 6, lane = threadIdx.x & 63;
  const int r = blockIdx.x * 4 + wid;      // [0, B*H*L)
  const int l = r & (LL - 1);
  const float4 p4 = *(const float4*)&pe[((size_t)l * 64 + lane) * 4]; // [[c,-s],[s,c]] row-major
#pragma unroll
  for (int t = 0; t < 2; t++) {
    u16* base = qkv + (size_t)t * BHLD + (size_t)r * DD + lane * 2;
    const float* sc = t ? ksc : qsc;
    ushort2 xx = *(const ushort2*)base;
    float x0 = bf2f(xx.x), x1 = bf2f(xx.y);
    float ss = x0*x0 + x1*x1;
#pragma unroll
    for (int m = 1; m < 64; m <<= 1) ss += __shfl_xor(ss, m, 64);
    float rr = rsqrtf(ss * (1.0f/128.0f) + 1e-6f);
    float y0 = x0 * rr * sc[lane*2], y1 = x1 * rr * sc[lane*2 + 1];
    ushort2 oo;
    oo.x = f2bf(p4.x * y0 + p4.y * y1);
    oo.y = f2bf(p4.z * y0 + p4.w * y1);
    *(ushort2*)base = oo;
  }
}

// ---------------- flash attention ----------------
// grid: (B*H) * (L/64) blocks; 4 waves/block; wave owns 16 q-rows.
// S^T = K_tile . Q^T  via 16x16x32  ->  C frag: S^T[k=quad*4+reg][q=lane&15]
// which IS the A-operand layout (m=lane&15=q, k=quad*4+j) for 16x16x16 PV. No transpose.
__global__ __launch_bounds__(256) void attn(
    const u16* __restrict__ qkv, u16* __restrict__ Oout)
{
  const int bh = blockIdx.x >> 5, qt = blockIdx.x & 31;
  const int wid = threadIdx.x >> 6, lane = threadIdx.x & 63;
  const int l15 = lane & 15, quad = lane >> 4;
  const int q0 = qt * 64 + wid * 16;
  const u16* qp = qkv + (size_t)bh * LL * DD;
  const u16* kp = qkv + (size_t)BHLD + (size_t)bh * LL * DD;
  const u16* vp = qkv + (size_t)2 * BHLD + (size_t)bh * DD * LL;  // V^T [D][L]

  bf16x8 qb[4];
#pragma unroll
  for (int f = 0; f < 4; f++)
    qb[f] = *(const bf16x8*)&qp[(size_t)(q0 + l15) * DD + f*32 + quad*8];

  float m_i = -3.0e38f, l_i = 0.f;
  f32x4 oacc[8] = {};

  for (int k0 = 0; k0 < LL; k0 += 16) {
    f32x4 s = {};
#pragma unroll
    for (int f = 0; f < 4; f++) {
      bf16x8 ka = *(const bf16x8*)&kp[(size_t)(k0 + l15) * DD + f*32 + quad*8];
      s = __builtin_amdgcn_mfma_f32_16x16x32_bf16(ka, qb[f], s, 0, 0, 0);
    }
    const float scl = 0.08838834764831845f;  // 1/sqrt(128)
    float s0 = s[0]*scl, s1 = s[1]*scl, s2 = s[2]*scl, s3 = s[3]*scl;
    float mt = fmaxf(fmaxf(s0, s1), fmaxf(s2, s3));
    mt = fmaxf(mt, __shfl_xor(mt, 16, 64));
    mt = fmaxf(mt, __shfl_xor(mt, 32, 64));
    float m_new = fmaxf(m_i, mt);
    float alpha = __expf(m_i - m_new);
    float p0 = __expf(s0 - m_new), p1 = __expf(s1 - m_new);
    float p2 = __expf(s2 - m_new), p3 = __expf(s3 - m_new);
    float ts = p0 + p1 + p2 + p3;
    ts += __shfl_xor(ts, 16, 64);
    ts += __shfl_xor(ts, 32, 64);
    l_i = l_i * alpha + ts;
    m_i = m_new;

    s16x4 pa;
    pa[0] = (short)f2bf(p0); pa[1] = (short)f2bf(p1);
    pa[2] = (short)f2bf(p2); pa[3] = (short)f2bf(p3);

    // alpha is held for q=lane&15; O-acc rows are q=quad*4+r -> broadcast within 16-lane group
    float ar[4];
#pragma unroll
    for (int r = 0; r < 4; r++) ar[r] = __shfl(alpha, (quad << 4) | (quad*4 + r), 64);
#pragma unroll
    for (int c = 0; c < 8; c++) {
      oacc[c][0] *= ar[0]; oacc[c][1] *= ar[1];
      oacc[c][2] *= ar[2]; oacc[c][3] *= ar[3];
      s16x4 vb = *(const s16x4*)&vp[(size_t)(c*16 + l15) * LL + k0 + quad*4];
      oacc[c] = __builtin_amdgcn_mfma_f32_16x16x16bf16_1k(pa, vb, oacc[c], 0, 0, 0);
    }
  }

  float lr[4];
#pragma unroll
  for (int r = 0; r < 4; r++) lr[r] = 1.0f / __shfl(l_i, (quad << 4) | (quad*4 + r), 64);
  const int b = bh >> 4, h = bh & 15;
#pragma unroll
  for (int c = 0; c < 8; c++)
#pragma unroll
    for (int r = 0; r < 4; r++) {
      int qrow = q0 + quad*4 + r;
      Oout[((size_t)(b*LL + qrow)) * N2 + h*DD + c*16 + l15] = f2bf(oacc[c][r] * lr[r]);
    }
}

// ---------------- launch ----------------

extern "C" void kernel_launch(void* const* d_in, const int* in_sizes, int n_in,
                              void* d_out, int out_size, void* d_ws, size_t ws_size,
                              hipStream_t stream) {
  const float* x       = (const float*)d_in[0];
  const float* pe      = (const float*)d_in[1];
  const float* qkv_w   = (const float*)d_in[2];
  const float* qkv_b   = (const float*)d_in[3];
  const float* q_scale = (const float*)d_in[4];
  const float* k_scale = (const float*)d_in[5];
  const float* proj_w  = (const float*)d_in[6];
  const float* proj_b  = (const float*)d_in[7];

  // workspace layout (bytes): needs 112 MB
  char* ws = (char*)d_ws;
  u16* xb   = (u16*)(ws + 0);           // [4096][2048] bf16   : 16 MB
  u16* w1t  = (u16*)(ws + 16777216);    // [6144][2048] bf16   : 24 MB
  u16* w2t  = (u16*)(ws + 41943040);    // [2048][2048] bf16   :  8 MB
  u16* qkv  = (u16*)(ws + 50331648);    // q,k [B,H,L,D], v [B,H,D,L] bf16 : 48 MB
  u16* attO = (u16*)(ws + 100663296);   // [4096][2048] bf16   : 16 MB

  f32_to_bf16_vec<<<(MM*KK/4)/256, 256, 0, stream>>>(x, xb, MM*KK/4);
  transpose_f32_bf16<<<dim3(N1/32, KK/32), 256, 0, stream>>>(qkv_w, w1t, KK, N1);
  transpose_f32_bf16<<<dim3(N2/32, KK/32), 256, 0, stream>>>(proj_w, w2t, KK, N2);
  gemm_bt<0><<<dim3(N1/128, MM/128), 256, 0, stream>>>(xb, w1t, qkv_b, (void*)qkv, MM, N1, KK);
  norm_rope<<<(BB*HB*LL)/4, 256, 0, stream>>>(qkv, pe, q_scale, k_scale);
  attn<<<BB*HB*(LL/64), 256, 0, stream>>>(qkv, attO);
  gemm_bt<1><<<dim3(N2/128, MM/128), 256, 0, stream>>>(attO, w2t, proj_b, d_out, MM, N2, KK);
}

// Round 3
// 556.546 us; speedup vs baseline: 1.8754x; 1.8754x over previous
//
#include <hip/hip_runtime.h>
#include <cstdint>
#include <cstddef>

// Problem constants
#define BB 2
#define HB 16
#define LL 2048
#define DD 128
#define MM 4096   // B*L
#define KK 2048   // DIM
#define N1 6144   // 3*DIM
#define N2 2048   // DIM
#define BHLD (BB*HB*LL*DD)  // 8388608 elements per q/k/v section

typedef unsigned short u16;
typedef __bf16 bf16x8 __attribute__((ext_vector_type(8)));   // 4 VGPRs: mfma 16x16x32 A/B operand
typedef short  s16x4  __attribute__((ext_vector_type(4)));   // 2 VGPRs: mfma 16x16x16 (_1k) A/B operand
typedef float  f32x4  __attribute__((ext_vector_type(4)));

__device__ __forceinline__ float bf2f(u16 u) {
  union { unsigned v; float f; } c; c.v = ((unsigned)u) << 16; return c.f;
}
__device__ __forceinline__ u16 f2bf(float f) {  // round-to-nearest-even
  unsigned u = __builtin_bit_cast(unsigned, f);
  return (u16)((u + 0x7FFFu + ((u >> 16) & 1u)) >> 16);
}

// ---------------- prep kernels ----------------

__global__ __launch_bounds__(256) void f32_to_bf16_vec(
    const float* __restrict__ in, u16* __restrict__ out, int n4) {
  int i = blockIdx.x * 256 + threadIdx.x;
  if (i >= n4) return;
  float4 v = ((const float4*)in)[i];
  ushort4 o;
  o.x = f2bf(v.x); o.y = f2bf(v.y); o.z = f2bf(v.z); o.w = f2bf(v.w);
  ((ushort4*)out)[i] = o;
}

// in: fp32 [R][C] row-major  ->  out: bf16 [C][R]
__global__ __launch_bounds__(256) void transpose_f32_bf16(
    const float* __restrict__ in, u16* __restrict__ out, int R, int C) {
  __shared__ float t[32][33];
  int c0 = blockIdx.x * 32, r0 = blockIdx.y * 32;
  int tx = threadIdx.x & 31, ty = threadIdx.x >> 5;  // 8 rows per pass
#pragma unroll
  for (int i = ty; i < 32; i += 8)
    t[i][tx] = in[(size_t)(r0 + i) * C + c0 + tx];
  __syncthreads();
#pragma unroll
  for (int i = ty; i < 32; i += 8)
    out[(size_t)(c0 + i) * R + r0 + tx] = f2bf(t[tx][i]);
}

// ---------------- GEMM (A [M][K] bf16, Bt [N][K] bf16) ----------------
// MODE 0: epilogue scatters into qkv sections: q,k as [B][H][L][D], v as [B][H][D][L] (bf16)
// MODE 1: plain fp32 row-major store [M][N]
template<int MODE>
__global__ __launch_bounds__(256) void gemm_bt(
    const u16* __restrict__ A, const u16* __restrict__ Bt,
    const float* __restrict__ bias, void* __restrict__ Cout,
    int Msz, int Nsz, int Ksz)
{
  __shared__ __align__(16) u16 As[128*32];
  __shared__ __align__(16) u16 Bs[128*32];
  const int tid  = threadIdx.x;
  const int lane = tid & 63;
  const int wid  = tid >> 6;
  const int l15  = lane & 15, quad = lane >> 4;
  const int m0 = blockIdx.y * 128, n0 = blockIdx.x * 128;
  const int wm = (wid >> 1) * 64, wn = (wid & 1) * 64;
  // staging: 512 16B-chunks per tile, 2 per thread; chunk c -> row c>>2, inner (c&3)*8 elems
  const int r0i = tid >> 2, in0 = (tid & 3) * 8;

  f32x4 acc[4][4] = {};

  for (int ks = 0; ks < Ksz; ks += 32) {
    __syncthreads();
    *(uint4*)&As[ r0i      *32 + in0] = *(const uint4*)&A [(size_t)(m0 + r0i)      * Ksz + ks + in0];
    *(uint4*)&As[(r0i + 64)*32 + in0] = *(const uint4*)&A [(size_t)(m0 + r0i + 64) * Ksz + ks + in0];
    *(uint4*)&Bs[ r0i      *32 + in0] = *(const uint4*)&Bt[(size_t)(n0 + r0i)      * Ksz + ks + in0];
    *(uint4*)&Bs[(r0i + 64)*32 + in0] = *(const uint4*)&Bt[(size_t)(n0 + r0i + 64) * Ksz + ks + in0];
    __syncthreads();
    bf16x8 af[4], bfr[4];
#pragma unroll
    for (int i = 0; i < 4; i++) af[i]  = *(const bf16x8*)&As[(wm + i*16 + l15)*32 + quad*8];
#pragma unroll
    for (int i = 0; i < 4; i++) bfr[i] = *(const bf16x8*)&Bs[(wn + i*16 + l15)*32 + quad*8];
#pragma unroll
    for (int i = 0; i < 4; i++)
#pragma unroll
      for (int j = 0; j < 4; j++)
        acc[i][j] = __builtin_amdgcn_mfma_f32_16x16x32_bf16(af[i], bfr[j], acc[i][j], 0, 0, 0);
  }

  // C/D layout: row = quad*4+reg (m), col = lane&15 (n)  [verified m89/m91]
#pragma unroll
  for (int i = 0; i < 4; i++) {
#pragma unroll
    for (int j = 0; j < 4; j++) {
      const int col = n0 + wn + j*16 + l15;
      const float bv = bias[col];
#pragma unroll
      for (int r = 0; r < 4; r++) {
        const int row = m0 + wm + i*16 + quad*4 + r;
        float v = acc[i][j][r] + bv;
        if (MODE == 0) {
          u16* qkv = (u16*)Cout;
          int t = col >> 11, hd = col & 2047, h = hd >> 7, d = hd & 127;
          int b = row >> 11, l = row & (LL - 1);
          size_t dst;
          if (t < 2) dst = (size_t)t * BHLD + (((size_t)(b*HB + h)) * LL + l) * DD + d;
          else       dst = (size_t)2 * BHLD + (((size_t)(b*HB + h)) * DD + d) * LL + l;
          qkv[dst] = f2bf(v);
        } else {
          ((float*)Cout)[(size_t)row * Nsz + col] = v;
        }
      }
    }
  }
}

// ---------------- fused RMSNorm + RoPE on q,k (in place, bf16) ----------------
// one wave per (b,h,l) row of 128; lane owns pair p = lane (D/2 = 64 pairs)
// q is additionally pre-scaled by 1/sqrt(D) so attn scores come out of MFMA ready.
__global__ __launch_bounds__(256) void norm_rope(
    u16* __restrict__ qkv, const float* __restrict__ pe,
    const float* __restrict__ qsc, const float* __restrict__ ksc)
{
  const int wid = threadIdx.x >> 6, lane = threadIdx.x & 63;
  const int r = blockIdx.x * 4 + wid;      // [0, B*H*L)
  const int l = r & (LL - 1);
  const float4 p4 = *(const float4*)&pe[((size_t)l * 64 + lane) * 4]; // [[c,-s],[s,c]] row-major
#pragma unroll
  for (int t = 0; t < 2; t++) {
    u16* base = qkv + (size_t)t * BHLD + (size_t)r * DD + lane * 2;
    const float* sc = t ? ksc : qsc;
    ushort2 xx = *(const ushort2*)base;
    float x0 = bf2f(xx.x), x1 = bf2f(xx.y);
    float ss = x0*x0 + x1*x1;
#pragma unroll
    for (int m = 1; m < 64; m <<= 1) ss += __shfl_xor(ss, m, 64);
    float rr = rsqrtf(ss * (1.0f/128.0f) + 1e-6f);
    if (t == 0) rr *= 0.08838834764831845f;  // fold 1/sqrt(128) into q
    float y0 = x0 * rr * sc[lane*2], y1 = x1 * rr * sc[lane*2 + 1];
    ushort2 oo;
    oo.x = f2bf(p4.x * y0 + p4.y * y1);
    oo.y = f2bf(p4.z * y0 + p4.w * y1);
    *(ushort2*)base = oo;
  }
}

// ---------------- flash attention v2 ----------------
// Fixed-shift softmax: q,k are RMS-normed so |s| = |q.k/sqrt(d)| <= sqrt(128) ~= 11.3.
// exp(s-12) can't overflow fp32 -> no running max, no rescale chain; final /l only.
// Block: 4 waves, Bq=128 (32 q-rows/wave), Bk=64 per iter. K,V^T staged in LDS
// (padded rows: <=2-way bank alias), register-prefetch of next tile before compute.
// S^T = K.Q^T (16x16x32) -> P lands in A-operand layout for PV (16x16x16). O in regs.
#define BKT 64
#define KPAD 136   // 128 + 8 elems
#define VPAD 68    // 64 + 4 elems
__global__ __launch_bounds__(256, 2) void attn(
    const u16* __restrict__ qkv, u16* __restrict__ Oout)
{
  __shared__ __align__(16) u16 Ks[BKT * KPAD];   // 17408 B
  __shared__ __align__(16) u16 Vs[DD * VPAD];    // 17408 B

  const int bh = blockIdx.x >> 4, qt = blockIdx.x & 15;
  const int wid = threadIdx.x >> 6, lane = threadIdx.x & 63;
  const int tid = threadIdx.x;
  const int l15 = lane & 15, quad = lane >> 4;
  const int q0 = qt * 128 + wid * 32;
  const u16* qp = qkv + (size_t)bh * LL * DD;
  const u16* kp = qkv + (size_t)BHLD + (size_t)bh * LL * DD;
  const u16* vp = qkv + (size_t)2 * BHLD + (size_t)bh * DD * LL;  // V^T [D][L]

  // staging geometry: 1024 16B-chunks per tile, 4 per thread
  int kr[4], kc[4], vr[4], vc[4];
#pragma unroll
  for (int i = 0; i < 4; i++) {
    int cc = tid + 256 * i;
    kr[i] = cc >> 4; kc[i] = (cc & 15) * 8;   // K: row in [0,64), col in [0,128)
    vr[i] = cc >> 3; vc[i] = (cc & 7) * 8;    // V: row d in [0,128), col k in [0,64)
  }

  // Q fragments, held for entire kernel: 2 qfrags x 4 d-frags
  bf16x8 qb[2][4];
#pragma unroll
  for (int qf = 0; qf < 2; qf++)
#pragma unroll
    for (int f = 0; f < 4; f++)
      qb[qf][f] = *(const bf16x8*)&qp[(size_t)(q0 + qf*16 + l15) * DD + f*32 + quad*8];

  float l_acc[2] = {0.f, 0.f};
  f32x4 oacc[2][8] = {};

  // prefetch tile 0
  uint4 pk[4], pv[4];
#pragma unroll
  for (int i = 0; i < 4; i++) {
    pk[i] = *(const uint4*)&kp[(size_t)kr[i] * DD + kc[i]];
    pv[i] = *(const uint4*)&vp[(size_t)vr[i] * LL + vc[i]];
  }

  for (int k0 = 0; k0 < LL; k0 += BKT) {
    __syncthreads();
#pragma unroll
    for (int i = 0; i < 4; i++) {
      *(uint4*)&Ks[kr[i] * KPAD + kc[i]] = pk[i];
      *(uint4*)&Vs[vr[i] * VPAD + vc[i]] = pv[i];
    }
    __syncthreads();

    if (k0 + BKT < LL) {  // wave-uniform; issue next-tile loads before compute
      const int kn = k0 + BKT;
#pragma unroll
      for (int i = 0; i < 4; i++) {
        pk[i] = *(const uint4*)&kp[(size_t)(kn + kr[i]) * DD + kc[i]];
        pv[i] = *(const uint4*)&vp[(size_t)vr[i] * LL + kn + vc[i]];
      }
    }

    // S^T = K . Q^T : m = 64 keys (4 tiles), n = 16 q per qfrag
    f32x4 s[2][4] = {};
#pragma unroll
    for (int f = 0; f < 4; f++) {
      bf16x8 kf[4];
#pragma unroll
      for (int mt = 0; mt < 4; mt++)
        kf[mt] = *(const bf16x8*)&Ks[(mt*16 + l15) * KPAD + f*32 + quad*8];
#pragma unroll
      for (int qf = 0; qf < 2; qf++)
#pragma unroll
        for (int mt = 0; mt < 4; mt++)
          s[qf][mt] = __builtin_amdgcn_mfma_f32_16x16x32_bf16(kf[mt], qb[qf][f], s[qf][mt], 0, 0, 0);
    }

    // exp(s - 12), accumulate l, pack P to bf16 A-frags
    s16x4 pa[2][4];
#pragma unroll
    for (int qf = 0; qf < 2; qf++) {
#pragma unroll
      for (int mt = 0; mt < 4; mt++) {
        float p0 = __expf(s[qf][mt][0] - 12.f);
        float p1 = __expf(s[qf][mt][1] - 12.f);
        float p2 = __expf(s[qf][mt][2] - 12.f);
        float p3 = __expf(s[qf][mt][3] - 12.f);
        l_acc[qf] += (p0 + p1) + (p2 + p3);
        pa[qf][mt][0] = (short)f2bf(p0); pa[qf][mt][1] = (short)f2bf(p1);
        pa[qf][mt][2] = (short)f2bf(p2); pa[qf][mt][3] = (short)f2bf(p3);
      }
    }

    // O += P . V : per k-chunk t (16 keys), 8 d-tiles, both qfrags share vb
#pragma unroll
    for (int t = 0; t < 4; t++) {
      s16x4 vb[8];
#pragma unroll
      for (int c = 0; c < 8; c++)
        vb[c] = *(const s16x4*)&Vs[(c*16 + l15) * VPAD + t*16 + quad*4];
#pragma unroll
      for (int qf = 0; qf < 2; qf++)
#pragma unroll
        for (int c = 0; c < 8; c++)
          oacc[qf][c] = __builtin_amdgcn_mfma_f32_16x16x16bf16_1k(pa[qf][t], vb[c], oacc[qf][c], 0, 0, 0);
    }
  }

  // final: reduce l across the 4 quad-replicas, normalize, store
#pragma unroll
  for (int qf = 0; qf < 2; qf++) {
    l_acc[qf] += __shfl_xor(l_acc[qf], 16, 64);
    l_acc[qf] += __shfl_xor(l_acc[qf], 32, 64);
  }
  const int b = bh >> 4, h = bh & 15;
#pragma unroll
  for (int qf = 0; qf < 2; qf++) {
    float lr[4];
#pragma unroll
    for (int r = 0; r < 4; r++)
      lr[r] = 1.0f / __shfl(l_acc[qf], (quad << 4) | (quad*4 + r), 64);
#pragma unroll
    for (int c = 0; c < 8; c++)
#pragma unroll
      for (int r = 0; r < 4; r++) {
        int qrow = q0 + qf*16 + quad*4 + r;
        Oout[((size_t)(b*LL + qrow)) * N2 + h*DD + c*16 + l15] = f2bf(oacc[qf][c][r] * lr[r]);
      }
  }
}

// ---------------- launch ----------------

extern "C" void kernel_launch(void* const* d_in, const int* in_sizes, int n_in,
                              void* d_out, int out_size, void* d_ws, size_t ws_size,
                              hipStream_t stream) {
  const float* x       = (const float*)d_in[0];
  const float* pe      = (const float*)d_in[1];
  const float* qkv_w   = (const float*)d_in[2];
  const float* qkv_b   = (const float*)d_in[3];
  const float* q_scale = (const float*)d_in[4];
  const float* k_scale = (const float*)d_in[5];
  const float* proj_w  = (const float*)d_in[6];
  const float* proj_b  = (const float*)d_in[7];

  // workspace layout (bytes): needs 112 MB
  char* ws = (char*)d_ws;
  u16* xb   = (u16*)(ws + 0);           // [4096][2048] bf16   : 16 MB
  u16* w1t  = (u16*)(ws + 16777216);    // [6144][2048] bf16   : 24 MB
  u16* w2t  = (u16*)(ws + 41943040);    // [2048][2048] bf16   :  8 MB
  u16* qkv  = (u16*)(ws + 50331648);    // q,k [B,H,L,D], v [B,H,D,L] bf16 : 48 MB
  u16* attO = (u16*)(ws + 100663296);   // [4096][2048] bf16   : 16 MB

  f32_to_bf16_vec<<<(MM*KK/4)/256, 256, 0, stream>>>(x, xb, MM*KK/4);
  transpose_f32_bf16<<<dim3(N1/32, KK/32), 256, 0, stream>>>(qkv_w, w1t, KK, N1);
  transpose_f32_bf16<<<dim3(N2/32, KK/32), 256, 0, stream>>>(proj_w, w2t, KK, N2);
  gemm_bt<0><<<dim3(N1/128, MM/128), 256, 0, stream>>>(xb, w1t, qkv_b, (void*)qkv, MM, N1, KK);
  norm_rope<<<(BB*HB*LL)/4, 256, 0, stream>>>(qkv, pe, q_scale, k_scale);
  attn<<<BB*HB*(LL/128), 256, 0, stream>>>(qkv, attO);
  gemm_bt<1><<<dim3(N2/128, MM/128), 256, 0, stream>>>(attO, w2t, proj_b, d_out, MM, N2, KK);
}

// Round 4
// 461.182 us; speedup vs baseline: 2.2632x; 1.2068x over previous
//
#include <hip/hip_runtime.h>
#include <cstdint>
#include <cstddef>

// Problem constants
#define BB 2
#define HB 16
#define LL 2048
#define DD 128
#define MM 4096   // B*L
#define KK 2048   // DIM
#define N1 6144   // 3*DIM
#define N2 2048   // DIM
#define BHLD (BB*HB*LL*DD)  // 8388608 elements per q/k/v section

typedef unsigned short u16;
typedef __bf16 bf16x8 __attribute__((ext_vector_type(8)));   // 4 VGPRs: mfma 16x16x32 A/B operand
typedef short  s16x4  __attribute__((ext_vector_type(4)));   // 2 VGPRs: mfma 16x16x16 (_1k) A/B operand
typedef float  f32x4  __attribute__((ext_vector_type(4)));

typedef __attribute__((address_space(1))) void* as1_ptr;
typedef __attribute__((address_space(3))) void* as3_ptr;

// async global->LDS, 16B per lane; LDS dest = wave-uniform base + lane*16 [m97/m104]
__device__ __forceinline__ void gload16(const void* g, void* l) {
  __builtin_amdgcn_global_load_lds((as1_ptr)g, (as3_ptr)l, 16, 0, 0);
}

__device__ __forceinline__ float bf2f(u16 u) {
  union { unsigned v; float f; } c; c.v = ((unsigned)u) << 16; return c.f;
}
__device__ __forceinline__ u16 f2bf(float f) {  // round-to-nearest-even
  unsigned u = __builtin_bit_cast(unsigned, f);
  return (u16)((u + 0x7FFFu + ((u >> 16) & 1u)) >> 16);
}

// ---------------- prep kernels ----------------

__global__ __launch_bounds__(256) void f32_to_bf16_vec(
    const float* __restrict__ in, u16* __restrict__ out, int n4) {
  int i = blockIdx.x * 256 + threadIdx.x;
  if (i >= n4) return;
  float4 v = ((const float4*)in)[i];
  ushort4 o;
  o.x = f2bf(v.x); o.y = f2bf(v.y); o.z = f2bf(v.z); o.w = f2bf(v.w);
  ((ushort4*)out)[i] = o;
}

// in: fp32 [R][C] row-major  ->  out: bf16 [C][R]
__global__ __launch_bounds__(256) void transpose_f32_bf16(
    const float* __restrict__ in, u16* __restrict__ out, int R, int C) {
  __shared__ float t[32][33];
  int c0 = blockIdx.x * 32, r0 = blockIdx.y * 32;
  int tx = threadIdx.x & 31, ty = threadIdx.x >> 5;  // 8 rows per pass
#pragma unroll
  for (int i = ty; i < 32; i += 8)
    t[i][tx] = in[(size_t)(r0 + i) * C + c0 + tx];
  __syncthreads();
#pragma unroll
  for (int i = ty; i < 32; i += 8)
    out[(size_t)(c0 + i) * R + r0 + tx] = f2bf(t[tx][i]);
}

// ---------------- GEMM (A [M][K] bf16, Bt [N][K] bf16) ----------------
// m97 pattern: global_load_lds width=16 staging, single-buffer, 2 barriers/iter.
// MODE 0: epilogue scatters into qkv sections: q,k as [B][H][L][D], v as [B][H][D][L] (bf16)
// MODE 1: plain fp32 row-major store [M][N]
template<int MODE>
__global__ __launch_bounds__(256) void gemm_bt(
    const u16* __restrict__ A, const u16* __restrict__ Bt,
    const float* __restrict__ bias, void* __restrict__ Cout,
    int Msz, int Nsz, int Ksz)
{
  __shared__ __align__(16) u16 As[128*32];
  __shared__ __align__(16) u16 Bs[128*32];
  const int tid  = threadIdx.x;
  const int lane = tid & 63;
  const int wid  = tid >> 6;
  const int l15  = lane & 15, quad = lane >> 4;
  const int m0 = blockIdx.y * 128, n0 = blockIdx.x * 128;
  const int wm = (wid >> 1) * 64, wn = (wid & 1) * 64;

  f32x4 acc[4][4] = {};

  for (int ks = 0; ks < Ksz; ks += 32) {
    __syncthreads();
    // staging: 512 16B-slots per tile; slot s -> row s>>2, elems (s&3)*8; wave issues 2 instrs each
#pragma unroll
    for (int j = 0; j < 2; j++) {
      const int s = (wid*2 + j)*64 + lane;
      const int row = s >> 2, ch = (s & 3) * 8;
      gload16(&A [(size_t)(m0 + row) * Ksz + ks + ch], &As[(wid*2 + j)*512]);
      gload16(&Bt[(size_t)(n0 + row) * Ksz + ks + ch], &Bs[(wid*2 + j)*512]);
    }
    __syncthreads();
    bf16x8 af[4], bfr[4];
#pragma unroll
    for (int i = 0; i < 4; i++) af[i]  = *(const bf16x8*)&As[(wm + i*16 + l15)*32 + quad*8];
#pragma unroll
    for (int i = 0; i < 4; i++) bfr[i] = *(const bf16x8*)&Bs[(wn + i*16 + l15)*32 + quad*8];
#pragma unroll
    for (int i = 0; i < 4; i++)
#pragma unroll
      for (int j = 0; j < 4; j++)
        acc[i][j] = __builtin_amdgcn_mfma_f32_16x16x32_bf16(af[i], bfr[j], acc[i][j], 0, 0, 0);
  }

  // C/D layout: row = quad*4+reg (m), col = lane&15 (n)  [verified m89/m91]
#pragma unroll
  for (int i = 0; i < 4; i++) {
#pragma unroll
    for (int j = 0; j < 4; j++) {
      const int col = n0 + wn + j*16 + l15;
      const float bv = bias[col];
#pragma unroll
      for (int r = 0; r < 4; r++) {
        const int row = m0 + wm + i*16 + quad*4 + r;
        float v = acc[i][j][r] + bv;
        if (MODE == 0) {
          u16* qkv = (u16*)Cout;
          int t = col >> 11, hd = col & 2047, h = hd >> 7, d = hd & 127;
          int b = row >> 11, l = row & (LL - 1);
          size_t dst;
          if (t < 2) dst = (size_t)t * BHLD + (((size_t)(b*HB + h)) * LL + l) * DD + d;
          else       dst = (size_t)2 * BHLD + (((size_t)(b*HB + h)) * DD + d) * LL + l;
          qkv[dst] = f2bf(v);
        } else {
          ((float*)Cout)[(size_t)row * Nsz + col] = v;
        }
      }
    }
  }
}

// ---------------- fused RMSNorm + RoPE on q,k (in place, bf16) ----------------
// one wave per (b,h,l) row of 128; lane owns pair p = lane (D/2 = 64 pairs)
// q is additionally pre-scaled by 1/sqrt(D) so attn scores come out of MFMA ready.
__global__ __launch_bounds__(256) void norm_rope(
    u16* __restrict__ qkv, const float* __restrict__ pe,
    const float* __restrict__ qsc, const float* __restrict__ ksc)
{
  const int wid = threadIdx.x >> 6, lane = threadIdx.x & 63;
  const int r = blockIdx.x * 4 + wid;      // [0, B*H*L)
  const int l = r & (LL - 1);
  const float4 p4 = *(const float4*)&pe[((size_t)l * 64 + lane) * 4]; // [[c,-s],[s,c]] row-major
#pragma unroll
  for (int t = 0; t < 2; t++) {
    u16* base = qkv + (size_t)t * BHLD + (size_t)r * DD + lane * 2;
    const float* sc = t ? ksc : qsc;
    ushort2 xx = *(const ushort2*)base;
    float x0 = bf2f(xx.x), x1 = bf2f(xx.y);
    float ss = x0*x0 + x1*x1;
#pragma unroll
    for (int m = 1; m < 64; m <<= 1) ss += __shfl_xor(ss, m, 64);
    float rr = rsqrtf(ss * (1.0f/128.0f) + 1e-6f);
    if (t == 0) rr *= 0.08838834764831845f;  // fold 1/sqrt(128) into q
    float y0 = x0 * rr * sc[lane*2], y1 = x1 * rr * sc[lane*2 + 1];
    ushort2 oo;
    oo.x = f2bf(p4.x * y0 + p4.y * y1);
    oo.y = f2bf(p4.z * y0 + p4.w * y1);
    *(ushort2*)base = oo;
  }
}

// ---------------- flash attention v3 ----------------
// Fixed-shift softmax (|s|<=sqrt(128) since q,k RMS-normed): no running max/rescale.
// Async global_load_lds double-buffered K/V tiles, 1 barrier per iter:
//   barrier -> issue async loads for tile i+1 -> compute tile i (loads drain at next barrier).
// LDS layout unpadded; bank conflicts broken by source-side XOR chunk swizzle
// (chunk c of row r stored at physical chunk c^(r&7); reader applies same XOR).
// S^T = K.Q^T (16x16x32) -> P lands in A-operand layout for PV (16x16x16). O in regs.
#define BKT 64
__global__ __launch_bounds__(256, 2) void attn(
    const u16* __restrict__ qkv, u16* __restrict__ Oout)
{
  __shared__ __align__(16) u16 Ksh[2][BKT * DD];   // 2 x 16 KB
  __shared__ __align__(16) u16 Vsh[2][DD * BKT];   // 2 x 16 KB

  const int bh = blockIdx.x >> 4, qt = blockIdx.x & 15;
  const int wid = threadIdx.x >> 6, lane = threadIdx.x & 63;
  const int l15 = lane & 15, quad = lane >> 4;
  const int q0 = qt * 128 + wid * 32;
  const u16* qp = qkv + (size_t)bh * LL * DD;
  const u16* kp = qkv + (size_t)BHLD + (size_t)bh * LL * DD;
  const u16* vp = qkv + (size_t)2 * BHLD + (size_t)bh * DD * LL;  // V^T [D][L]

  // Q fragments, held for entire kernel: 2 qfrags x 4 d-frags
  bf16x8 qb[2][4];
#pragma unroll
  for (int qf = 0; qf < 2; qf++)
#pragma unroll
    for (int f = 0; f < 4; f++)
      qb[qf][f] = *(const bf16x8*)&qp[(size_t)(q0 + qf*16 + l15) * DD + f*32 + quad*8];

  float l_acc[2] = {0.f, 0.f};
  f32x4 oacc[2][8] = {};

  // async stage of one K/V tile into buffer `buf` (wave issues 4+4 instrs)
  auto stage = [&](int buf, int k0) {
#pragma unroll
    for (int j = 0; j < 4; j++) {
      const int s = (wid*4 + j)*64 + lane;
      { // K: 64 rows x 16 chunks of 16B
        const int r = s >> 4, c = s & 15;
        const int lc = (c & 8) | ((c & 7) ^ (r & 7));
        gload16(&kp[(size_t)(k0 + r) * DD + lc*8], &Ksh[buf][(wid*4 + j)*512]);
      }
      { // V^T: 128 rows x 8 chunks of 16B
        const int r = s >> 3, c = s & 7;
        const int lc = c ^ (r & 7);
        gload16(&vp[(size_t)r * LL + k0 + lc*8], &Vsh[buf][(wid*4 + j)*512]);
      }
    }
  };

  stage(0, 0);
  int cur = 0;

  for (int k0 = 0; k0 < LL; k0 += BKT) {
    __syncthreads();                       // drains buf[cur] loads; frees buf[cur^1]
    if (k0 + BKT < LL) stage(cur ^ 1, k0 + BKT);

    // S^T = K . Q^T : m = 64 keys (4 tiles), n = 16 q per qfrag
    f32x4 s[2][4] = {};
#pragma unroll
    for (int f = 0; f < 4; f++) {
      bf16x8 kf[4];
#pragma unroll
      for (int mt = 0; mt < 4; mt++) {
        const int rr = mt*16 + l15;
        const int Lc = f*4 + quad;
        const int pc = (Lc & 8) | ((Lc & 7) ^ (rr & 7));
        kf[mt] = *(const bf16x8*)&Ksh[cur][rr*DD + pc*8];
      }
#pragma unroll
      for (int qf = 0; qf < 2; qf++)
#pragma unroll
        for (int mt = 0; mt < 4; mt++)
          s[qf][mt] = __builtin_amdgcn_mfma_f32_16x16x32_bf16(kf[mt], qb[qf][f], s[qf][mt], 0, 0, 0);
    }

    // exp(s - 12), accumulate l, pack P to bf16 A-frags
    s16x4 pa[2][4];
#pragma unroll
    for (int qf = 0; qf < 2; qf++) {
#pragma unroll
      for (int mt = 0; mt < 4; mt++) {
        float p0 = __expf(s[qf][mt][0] - 12.f);
        float p1 = __expf(s[qf][mt][1] - 12.f);
        float p2 = __expf(s[qf][mt][2] - 12.f);
        float p3 = __expf(s[qf][mt][3] - 12.f);
        l_acc[qf] += (p0 + p1) + (p2 + p3);
        pa[qf][mt][0] = (short)f2bf(p0); pa[qf][mt][1] = (short)f2bf(p1);
        pa[qf][mt][2] = (short)f2bf(p2); pa[qf][mt][3] = (short)f2bf(p3);
      }
    }

    // O += P . V : per k-chunk t (16 keys), 8 d-tiles, both qfrags share vb
#pragma unroll
    for (int t = 0; t < 4; t++) {
      s16x4 vb[8];
#pragma unroll
      for (int c = 0; c < 8; c++) {
        const int rv = c*16 + l15;
        const int pc = (t*2 + (quad >> 1)) ^ (l15 & 7);
        vb[c] = *(const s16x4*)&Vsh[cur][rv*BKT + pc*8 + (quad & 1)*4];
      }
#pragma unroll
      for (int qf = 0; qf < 2; qf++)
#pragma unroll
        for (int c = 0; c < 8; c++)
          oacc[qf][c] = __builtin_amdgcn_mfma_f32_16x16x16bf16_1k(pa[qf][t], vb[c], oacc[qf][c], 0, 0, 0);
    }
    cur ^= 1;
  }

  // final: reduce l across the 4 quad-replicas, normalize, store
#pragma unroll
  for (int qf = 0; qf < 2; qf++) {
    l_acc[qf] += __shfl_xor(l_acc[qf], 16, 64);
    l_acc[qf] += __shfl_xor(l_acc[qf], 32, 64);
  }
  const int b = bh >> 4, h = bh & 15;
#pragma unroll
  for (int qf = 0; qf < 2; qf++) {
    float lr[4];
#pragma unroll
    for (int r = 0; r < 4; r++)
      lr[r] = 1.0f / __shfl(l_acc[qf], (quad << 4) | (quad*4 + r), 64);
#pragma unroll
    for (int c = 0; c < 8; c++)
#pragma unroll
      for (int r = 0; r < 4; r++) {
        int qrow = q0 + qf*16 + quad*4 + r;
        Oout[((size_t)(b*LL + qrow)) * N2 + h*DD + c*16 + l15] = f2bf(oacc[qf][c][r] * lr[r]);
      }
  }
}

// ---------------- launch ----------------

extern "C" void kernel_launch(void* const* d_in, const int* in_sizes, int n_in,
                              void* d_out, int out_size, void* d_ws, size_t ws_size,
                              hipStream_t stream) {
  const float* x       = (const float*)d_in[0];
  const float* pe      = (const float*)d_in[1];
  const float* qkv_w   = (const float*)d_in[2];
  const float* qkv_b   = (const float*)d_in[3];
  const float* q_scale = (const float*)d_in[4];
  const float* k_scale = (const float*)d_in[5];
  const float* proj_w  = (const float*)d_in[6];
  const float* proj_b  = (const float*)d_in[7];

  // workspace layout (bytes): needs 112 MB
  char* ws = (char*)d_ws;
  u16* xb   = (u16*)(ws + 0);           // [4096][2048] bf16   : 16 MB
  u16* w1t  = (u16*)(ws + 16777216);    // [6144][2048] bf16   : 24 MB
  u16* w2t  = (u16*)(ws + 41943040);    // [2048][2048] bf16   :  8 MB
  u16* qkv  = (u16*)(ws + 50331648);    // q,k [B,H,L,D], v [B,H,D,L] bf16 : 48 MB
  u16* attO = (u16*)(ws + 100663296);   // [4096][2048] bf16   : 16 MB

  f32_to_bf16_vec<<<(MM*KK/4)/256, 256, 0, stream>>>(x, xb, MM*KK/4);
  transpose_f32_bf16<<<dim3(N1/32, KK/32), 256, 0, stream>>>(qkv_w, w1t, KK, N1);
  transpose_f32_bf16<<<dim3(N2/32, KK/32), 256, 0, stream>>>(proj_w, w2t, KK, N2);
  gemm_bt<0><<<dim3(N1/128, MM/128), 256, 0, stream>>>(xb, w1t, qkv_b, (void*)qkv, MM, N1, KK);
  norm_rope<<<(BB*HB*LL)/4, 256, 0, stream>>>(qkv, pe, q_scale, k_scale);
  attn<<<BB*HB*(LL/128), 256, 0, stream>>>(qkv, attO);
  gemm_bt<1><<<dim3(N2/128, MM/128), 256, 0, stream>>>(attO, w2t, proj_b, d_out, MM, N2, KK);
}

// Round 5
// 436.557 us; speedup vs baseline: 2.3908x; 1.0564x over previous
//
#include <hip/hip_runtime.h>
#include <cstdint>
#include <cstddef>

// Problem constants
#define BB 2
#define HB 16
#define LL 2048
#define DD 128
#define MM 4096   // B*L
#define KK 2048   // DIM
#define N1 6144   // 3*DIM
#define N2 2048   // DIM
#define BHLD (BB*HB*LL*DD)  // 8388608 elements per q/k/v section

typedef unsigned short u16;
typedef __bf16 bf16x8 __attribute__((ext_vector_type(8)));   // 4 VGPRs: mfma 16x16x32 A/B operand
typedef short  s16x4  __attribute__((ext_vector_type(4)));   // 2 VGPRs: mfma 16x16x16 (_1k) A/B operand
typedef float  f32x4  __attribute__((ext_vector_type(4)));

typedef __attribute__((address_space(1))) void* as1_ptr;
typedef __attribute__((address_space(3))) void* as3_ptr;

// async global->LDS, 16B per lane; LDS dest = wave-uniform base + lane*16 [m97/m104]
__device__ __forceinline__ void gload16(const void* g, void* l) {
  __builtin_amdgcn_global_load_lds((as1_ptr)g, (as3_ptr)l, 16, 0, 0);
}

__device__ __forceinline__ float bf2f(u16 u) {
  union { unsigned v; float f; } c; c.v = ((unsigned)u) << 16; return c.f;
}
__device__ __forceinline__ u16 f2bf(float f) {  // round-to-nearest-even
  unsigned u = __builtin_bit_cast(unsigned, f);
  return (u16)((u + 0x7FFFu + ((u >> 16) & 1u)) >> 16);
}

// ---------------- prep kernels ----------------

__global__ __launch_bounds__(256) void f32_to_bf16_vec(
    const float* __restrict__ in, u16* __restrict__ out, int n4) {
  int i = blockIdx.x * 256 + threadIdx.x;
  if (i >= n4) return;
  float4 v = ((const float4*)in)[i];
  ushort4 o;
  o.x = f2bf(v.x); o.y = f2bf(v.y); o.z = f2bf(v.z); o.w = f2bf(v.w);
  ((ushort4*)out)[i] = o;
}

// in: fp32 [R][C] row-major  ->  out: bf16 [C][R]
__global__ __launch_bounds__(256) void transpose_f32_bf16(
    const float* __restrict__ in, u16* __restrict__ out, int R, int C) {
  __shared__ float t[32][33];
  int c0 = blockIdx.x * 32, r0 = blockIdx.y * 32;
  int tx = threadIdx.x & 31, ty = threadIdx.x >> 5;  // 8 rows per pass
#pragma unroll
  for (int i = ty; i < 32; i += 8)
    t[i][tx] = in[(size_t)(r0 + i) * C + c0 + tx];
  __syncthreads();
#pragma unroll
  for (int i = ty; i < 32; i += 8)
    out[(size_t)(c0 + i) * R + r0 + tx] = f2bf(t[tx][i]);
}

// ---------------- GEMM (A [M][K] bf16, Bt [N][K] bf16) ----------------
// m97 pattern + BK=64 + XOR chunk swizzle:
//   - global_load_lds width=16 staging, single-buffer, 2 barriers per 64-wide K-iter
//   - tile rows stored as 8 chunks of 8 elems; logical chunk Lc lives at physical
//     chunk Lc^(r&7). Swizzle applied on the global SOURCE address (same 128B
//     segment, permuted) so coalescing is preserved; frag reads then hit all 8
//     bank-groups with 2 lanes each -> conflict-free [m136].
// MODE 0: epilogue scatters qkv: q,k as [B][H][L][D], v as [B][H][D][L] (bf16)
// MODE 1: plain fp32 row-major store [M][N]
template<int MODE>
__global__ __launch_bounds__(256) void gemm_bt(
    const u16* __restrict__ A, const u16* __restrict__ Bt,
    const float* __restrict__ bias, void* __restrict__ Cout,
    int Msz, int Nsz, int Ksz)
{
  __shared__ __align__(16) u16 As[128*64];   // 16 KB
  __shared__ __align__(16) u16 Bs[128*64];   // 16 KB
  const int tid  = threadIdx.x;
  const int lane = tid & 63;
  const int wid  = tid >> 6;
  const int l15  = lane & 15, quad = lane >> 4;
  const int m0 = blockIdx.y * 128, n0 = blockIdx.x * 128;
  const int wm = (wid >> 1) * 64, wn = (wid & 1) * 64;

  f32x4 acc[4][4] = {};

  for (int ks = 0; ks < Ksz; ks += 64) {
    __syncthreads();
    // staging: 1024 16B-slots per tile; slot s -> row s>>3, chunk s&7 (swizzled)
#pragma unroll
    for (int j = 0; j < 4; j++) {
      const int s = (wid*4 + j)*64 + lane;
      const int row = s >> 3, pc = (s & 7) ^ (row & 7);
      gload16(&A [(size_t)(m0 + row) * Ksz + ks + pc*8], &As[(wid*4 + j)*512]);
      gload16(&Bt[(size_t)(n0 + row) * Ksz + ks + pc*8], &Bs[(wid*4 + j)*512]);
    }
    __syncthreads();
#pragma unroll
    for (int kh = 0; kh < 2; kh++) {
      bf16x8 af[4], bfr[4];
#pragma unroll
      for (int i = 0; i < 4; i++) {
        const int r = wm + i*16 + l15;
        af[i]  = *(const bf16x8*)&As[r*64 + (((kh*4 + quad) ^ (r & 7)))*8];
      }
#pragma unroll
      for (int i = 0; i < 4; i++) {
        const int r = wn + i*16 + l15;
        bfr[i] = *(const bf16x8*)&Bs[r*64 + (((kh*4 + quad) ^ (r & 7)))*8];
      }
#pragma unroll
      for (int i = 0; i < 4; i++)
#pragma unroll
        for (int j = 0; j < 4; j++)
          acc[i][j] = __builtin_amdgcn_mfma_f32_16x16x32_bf16(af[i], bfr[j], acc[i][j], 0, 0, 0);
    }
  }

  // C/D layout: row = quad*4+reg (m), col = lane&15 (n)  [verified m89/m91]
#pragma unroll
  for (int i = 0; i < 4; i++) {
#pragma unroll
    for (int j = 0; j < 4; j++) {
      const int col = n0 + wn + j*16 + l15;
      const float bv = bias[col];
#pragma unroll
      for (int r = 0; r < 4; r++) {
        const int row = m0 + wm + i*16 + quad*4 + r;
        float v = acc[i][j][r] + bv;
        if (MODE == 0) {
          u16* qkv = (u16*)Cout;
          int t = col >> 11, hd = col & 2047, h = hd >> 7, d = hd & 127;
          int b = row >> 11, l = row & (LL - 1);
          size_t dst;
          if (t < 2) dst = (size_t)t * BHLD + (((size_t)(b*HB + h)) * LL + l) * DD + d;
          else       dst = (size_t)2 * BHLD + (((size_t)(b*HB + h)) * DD + d) * LL + l;
          qkv[dst] = f2bf(v);
        } else {
          ((float*)Cout)[(size_t)row * Nsz + col] = v;
        }
      }
    }
  }
}

// ---------------- fused RMSNorm + RoPE on q,k (in place, bf16) ----------------
// one wave per (b,h,l) row of 128; lane owns pair p = lane (D/2 = 64 pairs)
// q is additionally pre-scaled by 1/sqrt(D) so attn scores come out of MFMA ready.
__global__ __launch_bounds__(256) void norm_rope(
    u16* __restrict__ qkv, const float* __restrict__ pe,
    const float* __restrict__ qsc, const float* __restrict__ ksc)
{
  const int wid = threadIdx.x >> 6, lane = threadIdx.x & 63;
  const int r = blockIdx.x * 4 + wid;      // [0, B*H*L)
  const int l = r & (LL - 1);
  const float4 p4 = *(const float4*)&pe[((size_t)l * 64 + lane) * 4]; // [[c,-s],[s,c]] row-major
#pragma unroll
  for (int t = 0; t < 2; t++) {
    u16* base = qkv + (size_t)t * BHLD + (size_t)r * DD + lane * 2;
    const float* sc = t ? ksc : qsc;
    ushort2 xx = *(const ushort2*)base;
    float x0 = bf2f(xx.x), x1 = bf2f(xx.y);
    float ss = x0*x0 + x1*x1;
#pragma unroll
    for (int m = 1; m < 64; m <<= 1) ss += __shfl_xor(ss, m, 64);
    float rr = rsqrtf(ss * (1.0f/128.0f) + 1e-6f);
    if (t == 0) rr *= 0.08838834764831845f;  // fold 1/sqrt(128) into q
    float y0 = x0 * rr * sc[lane*2], y1 = x1 * rr * sc[lane*2 + 1];
    ushort2 oo;
    oo.x = f2bf(p4.x * y0 + p4.y * y1);
    oo.y = f2bf(p4.z * y0 + p4.w * y1);
    *(ushort2*)base = oo;
  }
}

// ---------------- flash attention v3 ----------------
// Fixed-shift softmax (|s|<=sqrt(128) since q,k RMS-normed): no running max/rescale.
// Async global_load_lds double-buffered K/V tiles, 1 barrier per iter:
//   barrier -> issue async loads for tile i+1 -> compute tile i (loads drain at next barrier).
// LDS layout unpadded; bank conflicts broken by source-side XOR chunk swizzle
// (chunk c of row r stored at physical chunk c^(r&7); reader applies same XOR).
// S^T = K.Q^T (16x16x32) -> P lands in A-operand layout for PV (16x16x16). O in regs.
#define BKT 64
__global__ __launch_bounds__(256, 2) void attn(
    const u16* __restrict__ qkv, u16* __restrict__ Oout)
{
  __shared__ __align__(16) u16 Ksh[2][BKT * DD];   // 2 x 16 KB
  __shared__ __align__(16) u16 Vsh[2][DD * BKT];   // 2 x 16 KB

  const int bh = blockIdx.x >> 4, qt = blockIdx.x & 15;
  const int wid = threadIdx.x >> 6, lane = threadIdx.x & 63;
  const int l15 = lane & 15, quad = lane >> 4;
  const int q0 = qt * 128 + wid * 32;
  const u16* qp = qkv + (size_t)bh * LL * DD;
  const u16* kp = qkv + (size_t)BHLD + (size_t)bh * LL * DD;
  const u16* vp = qkv + (size_t)2 * BHLD + (size_t)bh * DD * LL;  // V^T [D][L]

  // Q fragments, held for entire kernel: 2 qfrags x 4 d-frags
  bf16x8 qb[2][4];
#pragma unroll
  for (int qf = 0; qf < 2; qf++)
#pragma unroll
    for (int f = 0; f < 4; f++)
      qb[qf][f] = *(const bf16x8*)&qp[(size_t)(q0 + qf*16 + l15) * DD + f*32 + quad*8];

  float l_acc[2] = {0.f, 0.f};
  f32x4 oacc[2][8] = {};

  // async stage of one K/V tile into buffer `buf` (wave issues 4+4 instrs)
  auto stage = [&](int buf, int k0) {
#pragma unroll
    for (int j = 0; j < 4; j++) {
      const int s = (wid*4 + j)*64 + lane;
      { // K: 64 rows x 16 chunks of 16B
        const int r = s >> 4, c = s & 15;
        const int lc = (c & 8) | ((c & 7) ^ (r & 7));
        gload16(&kp[(size_t)(k0 + r) * DD + lc*8], &Ksh[buf][(wid*4 + j)*512]);
      }
      { // V^T: 128 rows x 8 chunks of 16B
        const int r = s >> 3, c = s & 7;
        const int lc = c ^ (r & 7);
        gload16(&vp[(size_t)r * LL + k0 + lc*8], &Vsh[buf][(wid*4 + j)*512]);
      }
    }
  };

  stage(0, 0);
  int cur = 0;

  for (int k0 = 0; k0 < LL; k0 += BKT) {
    __syncthreads();                       // drains buf[cur] loads; frees buf[cur^1]
    if (k0 + BKT < LL) stage(cur ^ 1, k0 + BKT);

    // S^T = K . Q^T : m = 64 keys (4 tiles), n = 16 q per qfrag
    f32x4 s[2][4] = {};
#pragma unroll
    for (int f = 0; f < 4; f++) {
      bf16x8 kf[4];
#pragma unroll
      for (int mt = 0; mt < 4; mt++) {
        const int rr = mt*16 + l15;
        const int Lc = f*4 + quad;
        const int pc = (Lc & 8) | ((Lc & 7) ^ (rr & 7));
        kf[mt] = *(const bf16x8*)&Ksh[cur][rr*DD + pc*8];
      }
#pragma unroll
      for (int qf = 0; qf < 2; qf++)
#pragma unroll
        for (int mt = 0; mt < 4; mt++)
          s[qf][mt] = __builtin_amdgcn_mfma_f32_16x16x32_bf16(kf[mt], qb[qf][f], s[qf][mt], 0, 0, 0);
    }

    // exp(s - 12), accumulate l, pack P to bf16 A-frags
    s16x4 pa[2][4];
#pragma unroll
    for (int qf = 0; qf < 2; qf++) {
#pragma unroll
      for (int mt = 0; mt < 4; mt++) {
        float p0 = __expf(s[qf][mt][0] - 12.f);
        float p1 = __expf(s[qf][mt][1] - 12.f);
        float p2 = __expf(s[qf][mt][2] - 12.f);
        float p3 = __expf(s[qf][mt][3] - 12.f);
        l_acc[qf] += (p0 + p1) + (p2 + p3);
        pa[qf][mt][0] = (short)f2bf(p0); pa[qf][mt][1] = (short)f2bf(p1);
        pa[qf][mt][2] = (short)f2bf(p2); pa[qf][mt][3] = (short)f2bf(p3);
      }
    }

    // O += P . V : per k-chunk t (16 keys), 8 d-tiles, both qfrags share vb
#pragma unroll
    for (int t = 0; t < 4; t++) {
      s16x4 vb[8];
#pragma unroll
      for (int c = 0; c < 8; c++) {
        const int rv = c*16 + l15;
        const int pc = (t*2 + (quad >> 1)) ^ (l15 & 7);
        vb[c] = *(const s16x4*)&Vsh[cur][rv*BKT + pc*8 + (quad & 1)*4];
      }
#pragma unroll
      for (int qf = 0; qf < 2; qf++)
#pragma unroll
        for (int c = 0; c < 8; c++)
          oacc[qf][c] = __builtin_amdgcn_mfma_f32_16x16x16bf16_1k(pa[qf][t], vb[c], oacc[qf][c], 0, 0, 0);
    }
    cur ^= 1;
  }

  // final: reduce l across the 4 quad-replicas, normalize, store
#pragma unroll
  for (int qf = 0; qf < 2; qf++) {
    l_acc[qf] += __shfl_xor(l_acc[qf], 16, 64);
    l_acc[qf] += __shfl_xor(l_acc[qf], 32, 64);
  }
  const int b = bh >> 4, h = bh & 15;
#pragma unroll
  for (int qf = 0; qf < 2; qf++) {
    float lr[4];
#pragma unroll
    for (int r = 0; r < 4; r++)
      lr[r] = 1.0f / __shfl(l_acc[qf], (quad << 4) | (quad*4 + r), 64);
#pragma unroll
    for (int c = 0; c < 8; c++)
#pragma unroll
      for (int r = 0; r < 4; r++) {
        int qrow = q0 + qf*16 + quad*4 + r;
        Oout[((size_t)(b*LL + qrow)) * N2 + h*DD + c*16 + l15] = f2bf(oacc[qf][c][r] * lr[r]);
      }
  }
}

// ---------------- launch ----------------

extern "C" void kernel_launch(void* const* d_in, const int* in_sizes, int n_in,
                              void* d_out, int out_size, void* d_ws, size_t ws_size,
                              hipStream_t stream) {
  const float* x       = (const float*)d_in[0];
  const float* pe      = (const float*)d_in[1];
  const float* qkv_w   = (const float*)d_in[2];
  const float* qkv_b   = (const float*)d_in[3];
  const float* q_scale = (const float*)d_in[4];
  const float* k_scale = (const float*)d_in[5];
  const float* proj_w  = (const float*)d_in[6];
  const float* proj_b  = (const float*)d_in[7];

  // workspace layout (bytes): needs 112 MB
  char* ws = (char*)d_ws;
  u16* xb   = (u16*)(ws + 0);           // [4096][2048] bf16   : 16 MB
  u16* w1t  = (u16*)(ws + 16777216);    // [6144][2048] bf16   : 24 MB
  u16* w2t  = (u16*)(ws + 41943040);    // [2048][2048] bf16   :  8 MB
  u16* qkv  = (u16*)(ws + 50331648);    // q,k [B,H,L,D], v [B,H,D,L] bf16 : 48 MB
  u16* attO = (u16*)(ws + 100663296);   // [4096][2048] bf16   : 16 MB

  f32_to_bf16_vec<<<(MM*KK/4)/256, 256, 0, stream>>>(x, xb, MM*KK/4);
  transpose_f32_bf16<<<dim3(N1/32, KK/32), 256, 0, stream>>>(qkv_w, w1t, KK, N1);
  transpose_f32_bf16<<<dim3(N2/32, KK/32), 256, 0, stream>>>(proj_w, w2t, KK, N2);
  gemm_bt<0><<<dim3(N1/128, MM/128), 256, 0, stream>>>(xb, w1t, qkv_b, (void*)qkv, MM, N1, KK);
  norm_rope<<<(BB*HB*LL)/4, 256, 0, stream>>>(qkv, pe, q_scale, k_scale);
  attn<<<BB*HB*(LL/128), 256, 0, stream>>>(qkv, attO);
  gemm_bt<1><<<dim3(N2/128, MM/128), 256, 0, stream>>>(attO, w2t, proj_b, d_out, MM, N2, KK);
}